// Round 20
// baseline (250.327 us; speedup 1.0000x reference)
//
#include <hip/hip_runtime.h>
#include <hip/hip_fp16.h>
#include <stdint.h>

#define F_IN 512
#define F_OUT 16
#define CB_SHIFT 8
#define CB_W 256          // nodes per coarse bucket
#define PER 6250          // edges per partition block (B1 = 512)
#define SORT_CAP 6400

typedef __attribute__((ext_vector_type(8))) short bf16x8;
typedef __attribute__((ext_vector_type(4))) float f32x4;

__device__ inline float4 f4_shfl_xor(float4 v, int mask) {
    float4 r;
    r.x = __shfl_xor(v.x, mask);
    r.y = __shfl_xor(v.y, mask);
    r.z = __shfl_xor(v.z, mask);
    r.w = __shfl_xor(v.w, mask);
    return r;
}

__device__ inline short f2bf(float f) {   // RNE fp32 -> bf16 bits
    unsigned u = __float_as_uint(f);
    unsigned r = (u + 0x7FFFu + ((u >> 16) & 1u)) >> 16;
    return (short)(unsigned short)r;
}

// gather one fp16 quarter-row (4 halves = 8B) and widen to float4
__device__ inline float4 ld_h4(const __half* __restrict__ xw, int s, int q) {
    const __half2* p = (const __half2*)(xw + ((size_t)s << 4)) + (q << 1);
    float2 f0 = __half22float2(p[0]);
    float2 f1 = __half22float2(p[1]);
    return make_float4(f0.x, f0.y, f1.x, f1.y);
}

// ---------------- MFMA gemm body (v17, UNSCALED output): wave handles pairs [ps,pe) stride NW ----------------
__device__ inline void gemm_pairs(const float* __restrict__ x, const float* __restrict__ W1,
                                  __half* __restrict__ xw1u, int N,
                                  int ps, int pe, int gw, int NW) {
    int lane = threadIdx.x & 63;
    int r16  = lane & 15;
    int kg   = lane >> 4;

    bf16x8 bfrag[16];
#pragma unroll
    for (int s = 0; s < 16; s++) {
        bf16x8 f;
#pragma unroll
        for (int i = 0; i < 8; i++)
            f[i] = f2bf(W1[(s * 32 + kg * 8 + i) * 16 + r16]);
        bfrag[s] = f;
    }

    int ntiles = (N + 15) >> 4;
    for (int pair = ps + gw; pair < pe; pair += NW) {
        int tile0 = pair * 2;
        int tile1 = tile0 + 1;
        int row0 = (tile0 << 4) + r16;
        int row1 = (tile1 << 4) + r16;
        const float* xr0 = x + (size_t)min(row0, N - 1) * F_IN + kg * 8;
        const float* xr1 = x + (size_t)min(row1, N - 1) * F_IN + kg * 8;
        bool t1ok = (tile1 < ntiles);
        f32x4 acc0 = {0.f, 0.f, 0.f, 0.f};
        f32x4 acc1 = {0.f, 0.f, 0.f, 0.f};
#pragma unroll
        for (int s = 0; s < 16; s++) {
            float4 xa0 = *(const float4*)(xr0 + s * 32);
            float4 xb0 = *(const float4*)(xr0 + s * 32 + 4);
            float4 xa1 = *(const float4*)(xr1 + s * 32);
            float4 xb1 = *(const float4*)(xr1 + s * 32 + 4);
            bf16x8 af0, af1;
            af0[0] = f2bf(xa0.x); af0[1] = f2bf(xa0.y); af0[2] = f2bf(xa0.z); af0[3] = f2bf(xa0.w);
            af0[4] = f2bf(xb0.x); af0[5] = f2bf(xb0.y); af0[6] = f2bf(xb0.z); af0[7] = f2bf(xb0.w);
            af1[0] = f2bf(xa1.x); af1[1] = f2bf(xa1.y); af1[2] = f2bf(xa1.z); af1[3] = f2bf(xa1.w);
            af1[4] = f2bf(xb1.x); af1[5] = f2bf(xb1.y); af1[6] = f2bf(xb1.z); af1[7] = f2bf(xb1.w);
            acc0 = __builtin_amdgcn_mfma_f32_16x16x32_bf16(af0, bfrag[s], acc0, 0, 0, 0);
            acc1 = __builtin_amdgcn_mfma_f32_16x16x32_bf16(af1, bfrag[s], acc1, 0, 0, 0);
        }
#pragma unroll
        for (int j = 0; j < 4; j++) {
            int r0 = (tile0 << 4) + kg * 4 + j;
            if (r0 < N) xw1u[((size_t)r0 << 4) + r16] = __float2half_rn(acc0[j]);
        }
        if (t1ok) {
#pragma unroll
            for (int j = 0; j < 4; j++) {
                int r1 = (tile1 << 4) + kg * 4 + j;
                if (r1 < N) xw1u[((size_t)r1 << 4) + r16] = __float2half_rn(acc1[j]);
            }
        }
    }
}

// ---------------- F1: chist (blocks 0..B-1) || gemm pairs [0,P1) ----------------
__global__ __launch_bounds__(512) void k_fuse1(const int* __restrict__ ei, int E, int K1, int B,
                                               int* __restrict__ cntT,
                                               const float* __restrict__ x, const float* __restrict__ W1,
                                               __half* __restrict__ xw1u, int N, int P1, int GB) {
    if ((int)blockIdx.x < B) {
        __shared__ int h[512];
        int t = threadIdx.x;
        h[t] = 0;
        __syncthreads();
        int e0 = blockIdx.x * PER, e1 = min(E, e0 + PER);
        for (int e = e0 + t; e < e1; e += 512)
            atomicAdd(&h[ei[(size_t)E + e] >> CB_SHIFT], 1);
        __syncthreads();
        for (int i = t; i < K1; i += 512) cntT[(size_t)i * B + blockIdx.x] = h[i];
    } else {
        int gw = ((int)blockIdx.x - B) * 8 + (int)(threadIdx.x >> 6);
        gemm_pairs(x, W1, xw1u, N, 0, P1, gw, GB * 8);
    }
}

// ---------------- P2a: per-bucket totals + scan over K1 (single block) ----------------
__global__ __launch_bounds__(512) void k_btot(const int* __restrict__ cntT, int B, int K1,
                                              int* __restrict__ bucketBase, int* __restrict__ bucketCnt) {
    __shared__ int sm[512];
    int k = threadIdx.x;
    int tot = 0;
    if (k < K1) {
        const int4* row = (const int4*)(cntT + (size_t)k * B);
        for (int b = 0; b < B / 4; b++) {
            int4 v = row[b];
            tot += v.x + v.y + v.z + v.w;
        }
    }
    sm[k] = tot;
    __syncthreads();
    for (int off = 1; off < 512; off <<= 1) {
        int add = (k >= off) ? sm[k - off] : 0;
        __syncthreads();
        sm[k] += add;
        __syncthreads();
    }
    if (k < K1) { bucketBase[k] = sm[k] - tot; bucketCnt[k] = tot; }
}

// ---------------- P2b: per-(bucket,block) bases — coalesced scan per bucket ----------------
__global__ __launch_bounds__(512) void k_bbase(const int* __restrict__ cntT, int B,
                                               const int* __restrict__ bucketBase,
                                               int* __restrict__ baseT) {
    __shared__ int sm[512];
    int k = blockIdx.x, t = threadIdx.x;
    int v = (t < B) ? cntT[(size_t)k * B + t] : 0;
    sm[t] = v;
    __syncthreads();
    for (int off = 1; off < 512; off <<= 1) {
        int add = (t >= off) ? sm[t - off] : 0;
        __syncthreads();
        sm[t] += add;
        __syncthreads();
    }
    if (t < B) baseT[(size_t)k * B + t] = bucketBase[k] + sm[t] - v;  // exclusive
}

// ---------------- F2: csort (blocks 0..B-1, cntT-reuse) || gemm pairs [P1,P2) ----------------
__global__ __launch_bounds__(512) void k_fuse2(const int* __restrict__ ei, int E, int K1, int B,
                                               const int* __restrict__ cntT, const int* __restrict__ baseT,
                                               unsigned* __restrict__ part,
                                               const float* __restrict__ x, const float* __restrict__ W1,
                                               __half* __restrict__ xw1u, int N, int P1, int P2, int GB) {
    if ((int)blockIdx.x < B) {
        __shared__ unsigned sorted[SORT_CAP];
        __shared__ int lb[512], cur[512], gb[512];
        int t = threadIdx.x;
        int e0 = blockIdx.x * PER, e1 = min(E, e0 + PER);
        int v = (t < K1) ? cntT[(size_t)t * B + blockIdx.x] : 0;
        lb[t] = v;
        __syncthreads();
        for (int off = 1; off < 512; off <<= 1) {
            int add = (t >= off) ? lb[t - off] : 0;
            __syncthreads();
            lb[t] += add;
            __syncthreads();
        }
        int excl = lb[t] - v;
        __syncthreads();
        lb[t] = excl;
        cur[t] = excl;
        if (t < K1) gb[t] = baseT[(size_t)t * B + blockIdx.x];
        __syncthreads();
        for (int e = e0 + t; e < e1; e += 512) {
            int s = ei[e];
            int d = ei[(size_t)E + e];
            int pos = atomicAdd(&cur[d >> CB_SHIFT], 1);           // LDS atomic
            sorted[pos] = ((unsigned)s << CB_SHIFT) | (unsigned)(d & (CB_W - 1));
        }
        __syncthreads();
        int g16 = t >> 4, ln = t & 15;
        for (int k = g16; k < K1; k += 32) {
            int s0 = lb[k];
            int s1 = cur[k];
            int g  = gb[k];
            for (int i = s0 + ln; i < s1; i += 16)
                part[(size_t)g + (i - s0)] = sorted[i];
        }
    } else {
        int gw = ((int)blockIdx.x - B) * 8 + (int)(threadIdx.x >> 6);
        gemm_pairs(x, W1, xw1u, N, P1, P2, gw, GB * 8);
    }
}

// ---------------- F3: prep2 (blocks 0..K1-1) || gemm pairs [P2,npairs) ----------------
__global__ __launch_bounds__(512) void k_fuse3(const unsigned* __restrict__ part,
                                               const int* __restrict__ bucketBase, const int* __restrict__ bucketCnt,
                                               int* __restrict__ hist, float* __restrict__ dinv,
                                               int* __restrict__ offsets, int* __restrict__ csr,
                                               const float* __restrict__ x, const float* __restrict__ W1,
                                               __half* __restrict__ xw1u, int N, int K1, int P2, int PE, int GB) {
    if ((int)blockIdx.x < K1) {
        __shared__ int fh[CB_W], fb[CB_W], cur[CB_W];
        int k = blockIdx.x, t = threadIdx.x;
        int base = bucketBase[k], cnt = bucketCnt[k];
        int d0 = k << CB_SHIFT;
        if (t < CB_W) fh[t] = 0;
        __syncthreads();
        for (int i = t; i < cnt; i += 512)
            atomicAdd(&fh[part[(size_t)base + i] & (CB_W - 1)], 1);
        __syncthreads();
        int v = 0;
        if (t < CB_W) { v = fh[t]; fb[t] = v; }
        __syncthreads();
        for (int off = 1; off < CB_W; off <<= 1) {
            int add = (t >= off && t < CB_W) ? fb[t - off] : 0;
            __syncthreads();
            if (t < CB_W) fb[t] += add;
            __syncthreads();
        }
        if (t < CB_W) {
            int excl = fb[t] - v;
            int n = d0 + t;
            if (n < N) {
                offsets[n] = base + excl;
                hist[n] = v;
                dinv[n] = rsqrtf((float)(v + 1));
            }
            cur[t] = excl;
        }
        __syncthreads();
        for (int i = t; i < cnt; i += 512) {
            unsigned e = part[(size_t)base + i];
            int pos = atomicAdd(&cur[e & (CB_W - 1)], 1);
            csr[(size_t)base + pos] = (int)(e >> CB_SHIFT);
        }
    } else {
        int gw = ((int)blockIdx.x - K1) * 8 + (int)(threadIdx.x >> 6);
        gemm_pairs(x, W1, xw1u, N, P2, PE, gw, GB * 8);
    }
}

// ---------------- K_scale: xw1 *= dinv[row] (fp16, 8 halves per thread) ----------------
__global__ __launch_bounds__(512) void k_scale(__half* __restrict__ xw, const float* __restrict__ dinv, int N) {
    int i = blockIdx.x * 512 + threadIdx.x;   // one uint4 = 8 halves = half a row
    if (i < N * 2) {
        float dn = dinv[i >> 1];
        uint4* p = (uint4*)xw + i;
        uint4 v = *p;
        __half2* h = (__half2*)&v;
#pragma unroll
        for (int j = 0; j < 4; j++) {
            float2 f = __half22float2(h[j]);
            h[j] = __floats2half2_rn(f.x * dn, f.y * dn);
        }
        *p = v;
    }
}

// ---------------- K6: agg1 + bias + ReLU + fused (h @ W2) * dinv — fp16 gathers, 8-deep ----------------
__global__ __launch_bounds__(256) void k_agg1(const __half* __restrict__ xw, const int* __restrict__ offsets,
                                              const int* __restrict__ hist, const float* __restrict__ dinv,
                                              const int* __restrict__ csr, const float* __restrict__ b1,
                                              const float* __restrict__ W2, __half* __restrict__ xw2p, int N) {
    __shared__ float W2s[256];
    if (threadIdx.x < 256) W2s[threadIdx.x] = W2[threadIdx.x];
    __syncthreads();

    int lane = threadIdx.x & 63;
    int wave = threadIdx.x >> 6;
    int grp  = lane >> 4;
    int sub  = lane & 15;
    int eo   = sub >> 2;
    int q    = sub & 3;
    int node = blockIdx.x * 16 + wave * 4 + grp;
    if (node >= N) return;

    int start = offsets[node], cnt = hist[node];
    float dn = dinv[node];
    float4 a0 = make_float4(0.f,0.f,0.f,0.f), a1 = a0, a2 = a0, a3 = a0;
    int i = 0;
    for (; i + 32 <= cnt; i += 32) {
        int s0 = csr[start + i + eo];
        int s1 = csr[start + i + 4 + eo];
        int s2 = csr[start + i + 8 + eo];
        int s3 = csr[start + i + 12 + eo];
        int s4 = csr[start + i + 16 + eo];
        int s5 = csr[start + i + 20 + eo];
        int s6 = csr[start + i + 24 + eo];
        int s7 = csr[start + i + 28 + eo];
        float4 v0 = ld_h4(xw, s0, q);
        float4 v1 = ld_h4(xw, s1, q);
        float4 v2 = ld_h4(xw, s2, q);
        float4 v3 = ld_h4(xw, s3, q);
        float4 v4 = ld_h4(xw, s4, q);
        float4 v5 = ld_h4(xw, s5, q);
        float4 v6 = ld_h4(xw, s6, q);
        float4 v7 = ld_h4(xw, s7, q);
        a0.x+=v0.x; a0.y+=v0.y; a0.z+=v0.z; a0.w+=v0.w;
        a1.x+=v1.x; a1.y+=v1.y; a1.z+=v1.z; a1.w+=v1.w;
        a2.x+=v2.x; a2.y+=v2.y; a2.z+=v2.z; a2.w+=v2.w;
        a3.x+=v3.x; a3.y+=v3.y; a3.z+=v3.z; a3.w+=v3.w;
        a0.x+=v4.x; a0.y+=v4.y; a0.z+=v4.z; a0.w+=v4.w;
        a1.x+=v5.x; a1.y+=v5.y; a1.z+=v5.z; a1.w+=v5.w;
        a2.x+=v6.x; a2.y+=v6.y; a2.z+=v6.z; a2.w+=v6.w;
        a3.x+=v7.x; a3.y+=v7.y; a3.z+=v7.z; a3.w+=v7.w;
    }
    for (; i + 16 <= cnt; i += 16) {
        int s0 = csr[start + i + eo];
        int s1 = csr[start + i + 4 + eo];
        int s2 = csr[start + i + 8 + eo];
        int s3 = csr[start + i + 12 + eo];
        float4 v0 = ld_h4(xw, s0, q);
        float4 v1 = ld_h4(xw, s1, q);
        float4 v2 = ld_h4(xw, s2, q);
        float4 v3 = ld_h4(xw, s3, q);
        a0.x+=v0.x; a0.y+=v0.y; a0.z+=v0.z; a0.w+=v0.w;
        a1.x+=v1.x; a1.y+=v1.y; a1.z+=v1.z; a1.w+=v1.w;
        a2.x+=v2.x; a2.y+=v2.y; a2.z+=v2.z; a2.w+=v2.w;
        a3.x+=v3.x; a3.y+=v3.y; a3.z+=v3.z; a3.w+=v3.w;
    }
    for (; i + 8 <= cnt; i += 8) {
        int s0 = csr[start + i + eo];
        int s1 = csr[start + i + 4 + eo];
        float4 v0 = ld_h4(xw, s0, q);
        float4 v1 = ld_h4(xw, s1, q);
        a0.x+=v0.x; a0.y+=v0.y; a0.z+=v0.z; a0.w+=v0.w;
        a1.x+=v1.x; a1.y+=v1.y; a1.z+=v1.z; a1.w+=v1.w;
    }
    for (; i < cnt; i += 4) {
        if (i + eo < cnt) {
            int s0 = csr[start + i + eo];
            float4 v0 = ld_h4(xw, s0, q);
            a0.x+=v0.x; a0.y+=v0.y; a0.z+=v0.z; a0.w+=v0.w;
        }
    }
    float4 acc;
    acc.x = a0.x+a1.x+a2.x+a3.x;
    acc.y = a0.y+a1.y+a2.y+a3.y;
    acc.z = a0.z+a1.z+a2.z+a3.z;
    acc.w = a0.w+a1.w+a2.w+a3.w;
    { float4 u = f4_shfl_xor(acc, 4); acc.x+=u.x; acc.y+=u.y; acc.z+=u.z; acc.w+=u.w; }
    { float4 u = f4_shfl_xor(acc, 8); acc.x+=u.x; acc.y+=u.y; acc.z+=u.z; acc.w+=u.w; }

    float4 sv = ld_h4(xw, node, q);
    float4 bq = ((const float4*)b1)[q];
    float4 h;
    h.x = fmaxf(dn * (acc.x + sv.x) + bq.x, 0.f);
    h.y = fmaxf(dn * (acc.y + sv.y) + bq.y, 0.f);
    h.z = fmaxf(dn * (acc.z + sv.z) + bq.z, 0.f);
    h.w = fmaxf(dn * (acc.w + sv.w) + bq.w, 0.f);

    // fused 16x16 GEMM: o_j = sum_r h[r] * W2[r][j], j = sub
    float o = 0.f;
#pragma unroll
    for (int a = 0; a < 4; a++) {
        int src = (grp << 4) + a;   // lane with q==a, eo==0 holds quarter a
        float h0 = __shfl(h.x, src);
        float h1 = __shfl(h.y, src);
        float h2 = __shfl(h.z, src);
        float h3 = __shfl(h.w, src);
        o += h0 * W2s[(a*4+0)*16 + sub] + h1 * W2s[(a*4+1)*16 + sub]
           + h2 * W2s[(a*4+2)*16 + sub] + h3 * W2s[(a*4+3)*16 + sub];
    }
    xw2p[((size_t)node << 4) + sub] = __float2half_rn(dn * o);
}

// ---------------- K7: agg2 + bias + ReLU + fused mean-pool partials — fp16 gathers ----------------
__global__ __launch_bounds__(256) void k_agg2(const __half* __restrict__ xw, const int* __restrict__ offsets,
                                              const int* __restrict__ hist, const float* __restrict__ dinv,
                                              const int* __restrict__ csr, const float* __restrict__ b2,
                                              float* __restrict__ partials, int N) {
    int lane = threadIdx.x & 63;
    int wave = threadIdx.x >> 6;
    int grp  = lane >> 4;
    int sub  = lane & 15;
    int eo   = sub >> 2;
    int q    = sub & 3;
    int node = blockIdx.x * 16 + wave * 4 + grp;

    float4 m = make_float4(0.f, 0.f, 0.f, 0.f);
    if (node < N) {
        int start = offsets[node], cnt = hist[node];
        float dn = dinv[node];
        float4 a0 = make_float4(0.f,0.f,0.f,0.f), a1 = a0, a2 = a0, a3 = a0;
        int i = 0;
        for (; i + 32 <= cnt; i += 32) {
            int s0 = csr[start + i + eo];
            int s1 = csr[start + i + 4 + eo];
            int s2 = csr[start + i + 8 + eo];
            int s3 = csr[start + i + 12 + eo];
            int s4 = csr[start + i + 16 + eo];
            int s5 = csr[start + i + 20 + eo];
            int s6 = csr[start + i + 24 + eo];
            int s7 = csr[start + i + 28 + eo];
            float4 v0 = ld_h4(xw, s0, q);
            float4 v1 = ld_h4(xw, s1, q);
            float4 v2 = ld_h4(xw, s2, q);
            float4 v3 = ld_h4(xw, s3, q);
            float4 v4 = ld_h4(xw, s4, q);
            float4 v5 = ld_h4(xw, s5, q);
            float4 v6 = ld_h4(xw, s6, q);
            float4 v7 = ld_h4(xw, s7, q);
            a0.x+=v0.x; a0.y+=v0.y; a0.z+=v0.z; a0.w+=v0.w;
            a1.x+=v1.x; a1.y+=v1.y; a1.z+=v1.z; a1.w+=v1.w;
            a2.x+=v2.x; a2.y+=v2.y; a2.z+=v2.z; a2.w+=v2.w;
            a3.x+=v3.x; a3.y+=v3.y; a3.z+=v3.z; a3.w+=v3.w;
            a0.x+=v4.x; a0.y+=v4.y; a0.z+=v4.z; a0.w+=v4.w;
            a1.x+=v5.x; a1.y+=v5.y; a1.z+=v5.z; a1.w+=v5.w;
            a2.x+=v6.x; a2.y+=v6.y; a2.z+=v6.z; a2.w+=v6.w;
            a3.x+=v7.x; a3.y+=v7.y; a3.z+=v7.z; a3.w+=v7.w;
        }
        for (; i + 16 <= cnt; i += 16) {
            int s0 = csr[start + i + eo];
            int s1 = csr[start + i + 4 + eo];
            int s2 = csr[start + i + 8 + eo];
            int s3 = csr[start + i + 12 + eo];
            float4 v0 = ld_h4(xw, s0, q);
            float4 v1 = ld_h4(xw, s1, q);
            float4 v2 = ld_h4(xw, s2, q);
            float4 v3 = ld_h4(xw, s3, q);
            a0.x+=v0.x; a0.y+=v0.y; a0.z+=v0.z; a0.w+=v0.w;
            a1.x+=v1.x; a1.y+=v1.y; a1.z+=v1.z; a1.w+=v1.w;
            a2.x+=v2.x; a2.y+=v2.y; a2.z+=v2.z; a2.w+=v2.w;
            a3.x+=v3.x; a3.y+=v3.y; a3.z+=v3.z; a3.w+=v3.w;
        }
        for (; i + 8 <= cnt; i += 8) {
            int s0 = csr[start + i + eo];
            int s1 = csr[start + i + 4 + eo];
            float4 v0 = ld_h4(xw, s0, q);
            float4 v1 = ld_h4(xw, s1, q);
            a0.x+=v0.x; a0.y+=v0.y; a0.z+=v0.z; a0.w+=v0.w;
            a1.x+=v1.x; a1.y+=v1.y; a1.z+=v1.z; a1.w+=v1.w;
        }
        for (; i < cnt; i += 4) {
            if (i + eo < cnt) {
                int s0 = csr[start + i + eo];
                float4 v0 = ld_h4(xw, s0, q);
                a0.x+=v0.x; a0.y+=v0.y; a0.z+=v0.z; a0.w+=v0.w;
            }
        }
        float4 acc;
        acc.x = a0.x+a1.x+a2.x+a3.x;
        acc.y = a0.y+a1.y+a2.y+a3.y;
        acc.z = a0.z+a1.z+a2.z+a3.z;
        acc.w = a0.w+a1.w+a2.w+a3.w;
        { float4 u = f4_shfl_xor(acc, 4); acc.x+=u.x; acc.y+=u.y; acc.z+=u.z; acc.w+=u.w; }
        { float4 u = f4_shfl_xor(acc, 8); acc.x+=u.x; acc.y+=u.y; acc.z+=u.z; acc.w+=u.w; }
        float4 sv = ld_h4(xw, node, q);
        float4 bq = ((const float4*)b2)[q];
        if (eo == 0) {
            m.x = fmaxf(dn * (acc.x + sv.x) + bq.x, 0.f);
            m.y = fmaxf(dn * (acc.y + sv.y) + bq.y, 0.f);
            m.z = fmaxf(dn * (acc.z + sv.z) + bq.z, 0.f);
            m.w = fmaxf(dn * (acc.w + sv.w) + bq.w, 0.f);
        }
    }
    { float4 u = f4_shfl_xor(m, 16); m.x+=u.x; m.y+=u.y; m.z+=u.z; m.w+=u.w; }
    { float4 u = f4_shfl_xor(m, 32); m.x+=u.x; m.y+=u.y; m.z+=u.z; m.w+=u.w; }
    __shared__ float smf[4][16];
    if (lane < 4) {
        smf[wave][q*4+0] = m.x;
        smf[wave][q*4+1] = m.y;
        smf[wave][q*4+2] = m.z;
        smf[wave][q*4+3] = m.w;
    }
    __syncthreads();
    if (threadIdx.x < 16) {
        float s = smf[0][threadIdx.x] + smf[1][threadIdx.x] + smf[2][threadIdx.x] + smf[3][threadIdx.x];
        partials[(size_t)blockIdx.x * 16 + threadIdx.x] = s;
    }
}

// ---------------- K8: final reduce + fc ----------------
__global__ void k_final(const float* __restrict__ partials, int NB, const float* __restrict__ fc_w,
                        const float* __restrict__ fc_b, float* __restrict__ out, float invN) {
    __shared__ float sm[64][16];
    int t = threadIdx.x;  // 1024 threads
    int g = t >> 4, j = t & 15;
    float s = 0.0f;
    for (int bk = g; bk < NB; bk += 64) s += partials[(size_t)bk * 16 + j];
    sm[g][j] = s;
    __syncthreads();
    for (int str = 32; str > 0; str >>= 1) {
        if (g < str) sm[g][j] += sm[g + str][j];
        __syncthreads();
    }
    if (t == 0) {
        float acc = fc_b[0];
#pragma unroll
        for (int jj = 0; jj < 16; jj++) acc += sm[0][jj] * invN * fc_w[jj];
        out[0] = acc;
    }
}

extern "C" void kernel_launch(void* const* d_in, const int* in_sizes, int n_in,
                              void* d_out, int out_size, void* d_ws, size_t ws_size,
                              hipStream_t stream) {
    const float* x   = (const float*)d_in[0];
    const int*   ei  = (const int*)d_in[1];
    const float* W1  = (const float*)d_in[2];
    const float* b1  = (const float*)d_in[3];
    const float* W2  = (const float*)d_in[4];
    const float* b2  = (const float*)d_in[5];
    const float* fcw = (const float*)d_in[6];
    const float* fcb = (const float*)d_in[7];
    float* out = (float*)d_out;

    int N = in_sizes[0] / F_IN;            // 100000
    int E = in_sizes[1] / 2;               // 3200000
    int K1 = (N + CB_W - 1) >> CB_SHIFT;   // 391 coarse buckets
    int B1 = (E + PER - 1) / PER;          // 512 partition blocks

    // ---- workspace carve-up (256B aligned) ----
    char* p = (char*)d_ws;
    auto alloc = [&](size_t bytes) {
        void* r = (void*)p;
        p += (bytes + 255) & ~(size_t)255;
        return r;
    };
    int*   cntT       = (int*)alloc((size_t)K1 * B1 * 4);
    int*   baseT      = (int*)alloc((size_t)K1 * B1 * 4);
    int*   bucketBase = (int*)alloc((size_t)K1 * 4);
    int*   bucketCnt  = (int*)alloc((size_t)K1 * 4);
    int*   hist       = (int*)alloc((size_t)N * 4);
    int*   offsets    = (int*)alloc((size_t)N * 4);
    float* dinv       = (float*)alloc((size_t)N * 4);
    int*   csr        = (int*)alloc((size_t)E * 4);
    unsigned* part    = (unsigned*)alloc((size_t)E * 4);    // 12.8 MB
    __half* xw1p      = (__half*)alloc((size_t)N * F_OUT * 2);  // 3.2 MB fp16
    __half* xw2p      = (__half*)alloc((size_t)N * F_OUT * 2);  // 3.2 MB fp16
    int NB_NODE = (N + 15) / 16;                            // 6250
    float* partials = (float*)alloc((size_t)NB_NODE * 16 * 4);

    int ntiles = (N + 15) >> 4;
    int npairs = (ntiles + 1) >> 1;        // 3125
    int P1 = npairs / 6;                   // ~520  (hidden under chist)
    int P2 = P1 + (npairs * 11) / 20;      // +~1718 (hidden under csort)
    int GB1 = 256, GB2 = 512, GB3 = 384;   // gemm blocks per fused launch

    k_fuse1<<<B1 + GB1, 512, 0, stream>>>(ei, E, K1, B1, cntT, x, W1, xw1p, N, P1, GB1);
    k_btot<<<1, 512, 0, stream>>>(cntT, B1, K1, bucketBase, bucketCnt);
    k_bbase<<<K1, 512, 0, stream>>>(cntT, B1, bucketBase, baseT);
    k_fuse2<<<B1 + GB2, 512, 0, stream>>>(ei, E, K1, B1, cntT, baseT, part, x, W1, xw1p, N, P1, P2, GB2);
    k_fuse3<<<K1 + GB3, 512, 0, stream>>>(part, bucketBase, bucketCnt, hist, dinv, offsets, csr,
                                          x, W1, xw1p, N, K1, P2, npairs, GB3);
    k_scale<<<(2 * N + 511) / 512, 512, 0, stream>>>(xw1p, dinv, N);

    k_agg1<<<NB_NODE, 256, 0, stream>>>(xw1p, offsets, hist, dinv, csr, b1, W2, xw2p, N);
    k_agg2<<<NB_NODE, 256, 0, stream>>>(xw2p, offsets, hist, dinv, csr, b2, partials, N);
    k_final<<<1, 1024, 0, stream>>>(partials, NB_NODE, fcw, fcb, out, 1.0f / (float)N);
}

// Round 21
// 211.465 us; speedup vs baseline: 1.1838x; 1.1838x over previous
//
#include <hip/hip_runtime.h>
#include <hip/hip_fp16.h>
#include <stdint.h>

#define F_IN 512
#define F_OUT 16
#define CB_SHIFT 8
#define CB_W 256          // nodes per coarse bucket
#define PER 6250          // edges per partition block (B1 = 512)
#define SORT_CAP 6400

typedef __attribute__((ext_vector_type(8))) short bf16x8;
typedef __attribute__((ext_vector_type(4))) float f32x4;

__device__ inline float4 f4_shfl_xor(float4 v, int mask) {
    float4 r;
    r.x = __shfl_xor(v.x, mask);
    r.y = __shfl_xor(v.y, mask);
    r.z = __shfl_xor(v.z, mask);
    r.w = __shfl_xor(v.w, mask);
    return r;
}

__device__ inline short f2bf(float f) {   // RNE fp32 -> bf16 bits
    unsigned u = __float_as_uint(f);
    unsigned r = (u + 0x7FFFu + ((u >> 16) & 1u)) >> 16;
    return (short)(unsigned short)r;
}

// gather one fp16 quarter-row (4 halves = 8B) and widen to float4
__device__ inline float4 ld_h4(const __half* __restrict__ xw, int s, int q) {
    const __half2* p = (const __half2*)(xw + ((size_t)s << 4)) + (q << 1);
    float2 f0 = __half22float2(p[0]);
    float2 f1 = __half22float2(p[1]);
    return make_float4(f0.x, f0.y, f1.x, f1.y);
}

// ---------------- P1: per-block LDS histogram over coarse buckets (TRANSPOSED out) ----------------
__global__ __launch_bounds__(256) void k_chist(const int* __restrict__ ei, int E, int K1, int B,
                                               int* __restrict__ cntT) {
    __shared__ int h[512];
    int t = threadIdx.x;
    for (int i = t; i < K1; i += 256) h[i] = 0;
    __syncthreads();
    int e0 = blockIdx.x * PER, e1 = min(E, e0 + PER);
    for (int e = e0 + t; e < e1; e += 256)
        atomicAdd(&h[ei[(size_t)E + e] >> CB_SHIFT], 1);
    __syncthreads();
    for (int i = t; i < K1; i += 256) cntT[(size_t)i * B + blockIdx.x] = h[i];
}

// ---------------- P2a: per-bucket totals + scan over K1 (single block) ----------------
__global__ __launch_bounds__(512) void k_btot(const int* __restrict__ cntT, int B, int K1,
                                              int* __restrict__ bucketBase, int* __restrict__ bucketCnt) {
    __shared__ int sm[512];
    int k = threadIdx.x;
    int tot = 0;
    if (k < K1) {
        const int4* row = (const int4*)(cntT + (size_t)k * B);
        for (int b = 0; b < B / 4; b++) {
            int4 v = row[b];
            tot += v.x + v.y + v.z + v.w;
        }
    }
    sm[k] = tot;
    __syncthreads();
    for (int off = 1; off < 512; off <<= 1) {
        int add = (k >= off) ? sm[k - off] : 0;
        __syncthreads();
        sm[k] += add;
        __syncthreads();
    }
    if (k < K1) { bucketBase[k] = sm[k] - tot; bucketCnt[k] = tot; }
}

// ---------------- P2b: per-(bucket,block) bases — coalesced scan per bucket ----------------
__global__ __launch_bounds__(512) void k_bbase(const int* __restrict__ cntT, int B,
                                               const int* __restrict__ bucketBase,
                                               int* __restrict__ baseT) {
    __shared__ int sm[512];
    int k = blockIdx.x, t = threadIdx.x;
    int v = (t < B) ? cntT[(size_t)k * B + t] : 0;
    sm[t] = v;
    __syncthreads();
    for (int off = 1; off < 512; off <<= 1) {
        int add = (t >= off) ? sm[t - off] : 0;
        __syncthreads();
        sm[t] += add;
        __syncthreads();
    }
    if (t < B) baseT[(size_t)k * B + t] = bucketBase[k] + sm[t] - v;  // exclusive
}

// ---------------- P3: LDS counting sort; histogram REUSED from cntT (saves an edge pass) ----------------
__global__ __launch_bounds__(512) void k_csort(const int* __restrict__ ei, int E, int K1, int B,
                                               const int* __restrict__ cntT,
                                               const int* __restrict__ baseT, unsigned* __restrict__ part) {
    __shared__ unsigned sorted[SORT_CAP];
    __shared__ int lb[512], cur[512], gb[512];
    int t = threadIdx.x;
    int e0 = blockIdx.x * PER, e1 = min(E, e0 + PER);
    int v = (t < K1) ? cntT[(size_t)t * B + blockIdx.x] : 0;   // this block's bucket counts
    lb[t] = v;
    __syncthreads();
    for (int off = 1; off < 512; off <<= 1) {
        int add = (t >= off) ? lb[t - off] : 0;
        __syncthreads();
        lb[t] += add;
        __syncthreads();
    }
    int excl = lb[t] - v;
    __syncthreads();
    lb[t] = excl;
    cur[t] = excl;
    if (t < K1) gb[t] = baseT[(size_t)t * B + blockIdx.x];
    __syncthreads();
    for (int e = e0 + t; e < e1; e += 512) {
        int s = ei[e];
        int d = ei[(size_t)E + e];
        int pos = atomicAdd(&cur[d >> CB_SHIFT], 1);           // LDS atomic
        sorted[pos] = ((unsigned)s << CB_SHIFT) | (unsigned)(d & (CB_W - 1));
    }
    __syncthreads();
    // 16-lane group per bucket: coalesced LDS reads, contiguous global writes
    int g16 = t >> 4, ln = t & 15;
    for (int k = g16; k < K1; k += 32) {
        int s0 = lb[k];
        int s1 = cur[k];
        int g  = gb[k];
        for (int i = s0 + ln; i < s1; i += 16)
            part[(size_t)g + (i - s0)] = sorted[i];
    }
}

// ---------------- P4: per coarse bucket: node hist/dinv/offsets + CSR (512 threads) ----------------
__global__ __launch_bounds__(512) void k_prep2(const unsigned* __restrict__ part,
                                               const int* __restrict__ bucketBase, const int* __restrict__ bucketCnt,
                                               int* __restrict__ hist, float* __restrict__ dinv,
                                               int* __restrict__ offsets, int* __restrict__ csr, int N) {
    __shared__ int fh[CB_W], fb[CB_W], cur[CB_W];
    int k = blockIdx.x, t = threadIdx.x;
    int base = bucketBase[k], cnt = bucketCnt[k];
    int d0 = k << CB_SHIFT;
    if (t < CB_W) fh[t] = 0;
    __syncthreads();
    for (int i = t; i < cnt; i += 512)
        atomicAdd(&fh[part[(size_t)base + i] & (CB_W - 1)], 1);
    __syncthreads();
    int v = 0;
    if (t < CB_W) { v = fh[t]; fb[t] = v; }
    __syncthreads();
    for (int off = 1; off < CB_W; off <<= 1) {
        int add = (t >= off && t < CB_W) ? fb[t - off] : 0;
        __syncthreads();
        if (t < CB_W) fb[t] += add;
        __syncthreads();
    }
    if (t < CB_W) {
        int excl = fb[t] - v;
        int n = d0 + t;
        if (n < N) {
            offsets[n] = base + excl;
            hist[n] = v;
            dinv[n] = rsqrtf((float)(v + 1));
        }
        cur[t] = excl;
    }
    __syncthreads();
    for (int i = t; i < cnt; i += 512) {
        unsigned e = part[(size_t)base + i];
        int pos = atomicAdd(&cur[e & (CB_W - 1)], 1);
        csr[(size_t)base + pos] = (int)(e >> CB_SHIFT);
    }
}

// ---------------- K5 v17: xw1' = fp16(dinv * (x @ W1)) via MFMA — 2 tiles/wave ----------------
// Wave owns PAIRS of 16-row tiles. B-frags (all of W, bf16) built once into 64 VGPRs.
// Per K-step: 4 independent b128 loads (both tiles) then 2 MFMAs. No LDS, no barriers.
// D-layout (m89-verified): lane holds C[(lane>>4)*4 + j][lane&15].
__global__ __launch_bounds__(256, 4) void k_gemm1(const float* __restrict__ x, const float* __restrict__ W1,
                                                  const float* __restrict__ dinv, __half* __restrict__ xw1p, int N) {
    int lane = threadIdx.x & 63;
    int wv   = blockIdx.x * 4 + (threadIdx.x >> 6);
    int nw   = gridDim.x * 4;
    int r16  = lane & 15;
    int kg   = lane >> 4;

    // B-fragments: bfrag[s][i] = bf16(W1[(s*32 + kg*8 + i)*16 + r16])
    bf16x8 bfrag[16];
#pragma unroll
    for (int s = 0; s < 16; s++) {
        bf16x8 f;
#pragma unroll
        for (int i = 0; i < 8; i++)
            f[i] = f2bf(W1[(s * 32 + kg * 8 + i) * 16 + r16]);
        bfrag[s] = f;
    }

    int ntiles = (N + 15) >> 4;
    int npairs = (ntiles + 1) >> 1;
    for (int pair = wv; pair < npairs; pair += nw) {
        int tile0 = pair * 2;
        int tile1 = tile0 + 1;
        int row0 = (tile0 << 4) + r16;
        int row1 = (tile1 << 4) + r16;
        const float* xr0 = x + (size_t)min(row0, N - 1) * F_IN + kg * 8;
        const float* xr1 = x + (size_t)min(row1, N - 1) * F_IN + kg * 8;
        bool t1ok = (tile1 < ntiles);
        f32x4 acc0 = {0.f, 0.f, 0.f, 0.f};
        f32x4 acc1 = {0.f, 0.f, 0.f, 0.f};
#pragma unroll
        for (int s = 0; s < 16; s++) {
            float4 xa0 = *(const float4*)(xr0 + s * 32);
            float4 xb0 = *(const float4*)(xr0 + s * 32 + 4);
            float4 xa1 = *(const float4*)(xr1 + s * 32);
            float4 xb1 = *(const float4*)(xr1 + s * 32 + 4);
            bf16x8 af0, af1;
            af0[0] = f2bf(xa0.x); af0[1] = f2bf(xa0.y); af0[2] = f2bf(xa0.z); af0[3] = f2bf(xa0.w);
            af0[4] = f2bf(xb0.x); af0[5] = f2bf(xb0.y); af0[6] = f2bf(xb0.z); af0[7] = f2bf(xb0.w);
            af1[0] = f2bf(xa1.x); af1[1] = f2bf(xa1.y); af1[2] = f2bf(xa1.z); af1[3] = f2bf(xa1.w);
            af1[4] = f2bf(xb1.x); af1[5] = f2bf(xb1.y); af1[6] = f2bf(xb1.z); af1[7] = f2bf(xb1.w);
            acc0 = __builtin_amdgcn_mfma_f32_16x16x32_bf16(af0, bfrag[s], acc0, 0, 0, 0);
            acc1 = __builtin_amdgcn_mfma_f32_16x16x32_bf16(af1, bfrag[s], acc1, 0, 0, 0);
        }
#pragma unroll
        for (int j = 0; j < 4; j++) {
            int r0 = (tile0 << 4) + kg * 4 + j;
            if (r0 < N) {
                float dn = dinv[r0];
                xw1p[((size_t)r0 << 4) + r16] = __float2half_rn(dn * acc0[j]);
            }
        }
        if (t1ok) {
#pragma unroll
            for (int j = 0; j < 4; j++) {
                int r1 = (tile1 << 4) + kg * 4 + j;
                if (r1 < N) {
                    float dn = dinv[r1];
                    xw1p[((size_t)r1 << 4) + r16] = __float2half_rn(dn * acc1[j]);
                }
            }
        }
    }
}

// ---------------- K6: agg1 + bias + ReLU + fused (h @ W2) * dinv — fp16 gathers, 8-deep ----------------
// 16-lane group per node: lane = eo*4 + q (4 edge slots x 4 quarters)
__global__ __launch_bounds__(256) void k_agg1(const __half* __restrict__ xw, const int* __restrict__ offsets,
                                              const int* __restrict__ hist, const float* __restrict__ dinv,
                                              const int* __restrict__ csr, const float* __restrict__ b1,
                                              const float* __restrict__ W2, __half* __restrict__ xw2p, int N) {
    __shared__ float W2s[256];
    if (threadIdx.x < 256) W2s[threadIdx.x] = W2[threadIdx.x];
    __syncthreads();

    int lane = threadIdx.x & 63;
    int wave = threadIdx.x >> 6;
    int grp  = lane >> 4;
    int sub  = lane & 15;
    int eo   = sub >> 2;
    int q    = sub & 3;
    int node = blockIdx.x * 16 + wave * 4 + grp;
    if (node >= N) return;

    int start = offsets[node], cnt = hist[node];
    float dn = dinv[node];
    float4 a0 = make_float4(0.f,0.f,0.f,0.f), a1 = a0, a2 = a0, a3 = a0;
    int i = 0;
    for (; i + 32 <= cnt; i += 32) {
        int s0 = csr[start + i + eo];
        int s1 = csr[start + i + 4 + eo];
        int s2 = csr[start + i + 8 + eo];
        int s3 = csr[start + i + 12 + eo];
        int s4 = csr[start + i + 16 + eo];
        int s5 = csr[start + i + 20 + eo];
        int s6 = csr[start + i + 24 + eo];
        int s7 = csr[start + i + 28 + eo];
        float4 v0 = ld_h4(xw, s0, q);
        float4 v1 = ld_h4(xw, s1, q);
        float4 v2 = ld_h4(xw, s2, q);
        float4 v3 = ld_h4(xw, s3, q);
        float4 v4 = ld_h4(xw, s4, q);
        float4 v5 = ld_h4(xw, s5, q);
        float4 v6 = ld_h4(xw, s6, q);
        float4 v7 = ld_h4(xw, s7, q);
        a0.x+=v0.x; a0.y+=v0.y; a0.z+=v0.z; a0.w+=v0.w;
        a1.x+=v1.x; a1.y+=v1.y; a1.z+=v1.z; a1.w+=v1.w;
        a2.x+=v2.x; a2.y+=v2.y; a2.z+=v2.z; a2.w+=v2.w;
        a3.x+=v3.x; a3.y+=v3.y; a3.z+=v3.z; a3.w+=v3.w;
        a0.x+=v4.x; a0.y+=v4.y; a0.z+=v4.z; a0.w+=v4.w;
        a1.x+=v5.x; a1.y+=v5.y; a1.z+=v5.z; a1.w+=v5.w;
        a2.x+=v6.x; a2.y+=v6.y; a2.z+=v6.z; a2.w+=v6.w;
        a3.x+=v7.x; a3.y+=v7.y; a3.z+=v7.z; a3.w+=v7.w;
    }
    for (; i + 16 <= cnt; i += 16) {
        int s0 = csr[start + i + eo];
        int s1 = csr[start + i + 4 + eo];
        int s2 = csr[start + i + 8 + eo];
        int s3 = csr[start + i + 12 + eo];
        float4 v0 = ld_h4(xw, s0, q);
        float4 v1 = ld_h4(xw, s1, q);
        float4 v2 = ld_h4(xw, s2, q);
        float4 v3 = ld_h4(xw, s3, q);
        a0.x+=v0.x; a0.y+=v0.y; a0.z+=v0.z; a0.w+=v0.w;
        a1.x+=v1.x; a1.y+=v1.y; a1.z+=v1.z; a1.w+=v1.w;
        a2.x+=v2.x; a2.y+=v2.y; a2.z+=v2.z; a2.w+=v2.w;
        a3.x+=v3.x; a3.y+=v3.y; a3.z+=v3.z; a3.w+=v3.w;
    }
    for (; i + 8 <= cnt; i += 8) {
        int s0 = csr[start + i + eo];
        int s1 = csr[start + i + 4 + eo];
        float4 v0 = ld_h4(xw, s0, q);
        float4 v1 = ld_h4(xw, s1, q);
        a0.x+=v0.x; a0.y+=v0.y; a0.z+=v0.z; a0.w+=v0.w;
        a1.x+=v1.x; a1.y+=v1.y; a1.z+=v1.z; a1.w+=v1.w;
    }
    for (; i < cnt; i += 4) {
        if (i + eo < cnt) {
            int s0 = csr[start + i + eo];
            float4 v0 = ld_h4(xw, s0, q);
            a0.x+=v0.x; a0.y+=v0.y; a0.z+=v0.z; a0.w+=v0.w;
        }
    }
    float4 acc;
    acc.x = a0.x+a1.x+a2.x+a3.x;
    acc.y = a0.y+a1.y+a2.y+a3.y;
    acc.z = a0.z+a1.z+a2.z+a3.z;
    acc.w = a0.w+a1.w+a2.w+a3.w;
    { float4 u = f4_shfl_xor(acc, 4); acc.x+=u.x; acc.y+=u.y; acc.z+=u.z; acc.w+=u.w; }
    { float4 u = f4_shfl_xor(acc, 8); acc.x+=u.x; acc.y+=u.y; acc.z+=u.z; acc.w+=u.w; }

    float4 sv = ld_h4(xw, node, q);
    float4 bq = ((const float4*)b1)[q];
    float4 h;
    h.x = fmaxf(dn * (acc.x + sv.x) + bq.x, 0.f);
    h.y = fmaxf(dn * (acc.y + sv.y) + bq.y, 0.f);
    h.z = fmaxf(dn * (acc.z + sv.z) + bq.z, 0.f);
    h.w = fmaxf(dn * (acc.w + sv.w) + bq.w, 0.f);

    // fused 16x16 GEMM: o_j = sum_r h[r] * W2[r][j], j = sub
    float o = 0.f;
#pragma unroll
    for (int a = 0; a < 4; a++) {
        int src = (grp << 4) + a;   // lane with q==a, eo==0 holds quarter a
        float h0 = __shfl(h.x, src);
        float h1 = __shfl(h.y, src);
        float h2 = __shfl(h.z, src);
        float h3 = __shfl(h.w, src);
        o += h0 * W2s[(a*4+0)*16 + sub] + h1 * W2s[(a*4+1)*16 + sub]
           + h2 * W2s[(a*4+2)*16 + sub] + h3 * W2s[(a*4+3)*16 + sub];
    }
    xw2p[((size_t)node << 4) + sub] = __float2half_rn(dn * o);
}

// ---------------- K7: agg2 + bias + ReLU + fused mean-pool partials — fp16 gathers ----------------
__global__ __launch_bounds__(256) void k_agg2(const __half* __restrict__ xw, const int* __restrict__ offsets,
                                              const int* __restrict__ hist, const float* __restrict__ dinv,
                                              const int* __restrict__ csr, const float* __restrict__ b2,
                                              float* __restrict__ partials, int N) {
    int lane = threadIdx.x & 63;
    int wave = threadIdx.x >> 6;
    int grp  = lane >> 4;
    int sub  = lane & 15;
    int eo   = sub >> 2;
    int q    = sub & 3;
    int node = blockIdx.x * 16 + wave * 4 + grp;

    float4 m = make_float4(0.f, 0.f, 0.f, 0.f);
    if (node < N) {
        int start = offsets[node], cnt = hist[node];
        float dn = dinv[node];
        float4 a0 = make_float4(0.f,0.f,0.f,0.f), a1 = a0, a2 = a0, a3 = a0;
        int i = 0;
        for (; i + 32 <= cnt; i += 32) {
            int s0 = csr[start + i + eo];
            int s1 = csr[start + i + 4 + eo];
            int s2 = csr[start + i + 8 + eo];
            int s3 = csr[start + i + 12 + eo];
            int s4 = csr[start + i + 16 + eo];
            int s5 = csr[start + i + 20 + eo];
            int s6 = csr[start + i + 24 + eo];
            int s7 = csr[start + i + 28 + eo];
            float4 v0 = ld_h4(xw, s0, q);
            float4 v1 = ld_h4(xw, s1, q);
            float4 v2 = ld_h4(xw, s2, q);
            float4 v3 = ld_h4(xw, s3, q);
            float4 v4 = ld_h4(xw, s4, q);
            float4 v5 = ld_h4(xw, s5, q);
            float4 v6 = ld_h4(xw, s6, q);
            float4 v7 = ld_h4(xw, s7, q);
            a0.x+=v0.x; a0.y+=v0.y; a0.z+=v0.z; a0.w+=v0.w;
            a1.x+=v1.x; a1.y+=v1.y; a1.z+=v1.z; a1.w+=v1.w;
            a2.x+=v2.x; a2.y+=v2.y; a2.z+=v2.z; a2.w+=v2.w;
            a3.x+=v3.x; a3.y+=v3.y; a3.z+=v3.z; a3.w+=v3.w;
            a0.x+=v4.x; a0.y+=v4.y; a0.z+=v4.z; a0.w+=v4.w;
            a1.x+=v5.x; a1.y+=v5.y; a1.z+=v5.z; a1.w+=v5.w;
            a2.x+=v6.x; a2.y+=v6.y; a2.z+=v6.z; a2.w+=v6.w;
            a3.x+=v7.x; a3.y+=v7.y; a3.z+=v7.z; a3.w+=v7.w;
        }
        for (; i + 16 <= cnt; i += 16) {
            int s0 = csr[start + i + eo];
            int s1 = csr[start + i + 4 + eo];
            int s2 = csr[start + i + 8 + eo];
            int s3 = csr[start + i + 12 + eo];
            float4 v0 = ld_h4(xw, s0, q);
            float4 v1 = ld_h4(xw, s1, q);
            float4 v2 = ld_h4(xw, s2, q);
            float4 v3 = ld_h4(xw, s3, q);
            a0.x+=v0.x; a0.y+=v0.y; a0.z+=v0.z; a0.w+=v0.w;
            a1.x+=v1.x; a1.y+=v1.y; a1.z+=v1.z; a1.w+=v1.w;
            a2.x+=v2.x; a2.y+=v2.y; a2.z+=v2.z; a2.w+=v2.w;
            a3.x+=v3.x; a3.y+=v3.y; a3.z+=v3.z; a3.w+=v3.w;
        }
        for (; i + 8 <= cnt; i += 8) {
            int s0 = csr[start + i + eo];
            int s1 = csr[start + i + 4 + eo];
            float4 v0 = ld_h4(xw, s0, q);
            float4 v1 = ld_h4(xw, s1, q);
            a0.x+=v0.x; a0.y+=v0.y; a0.z+=v0.z; a0.w+=v0.w;
            a1.x+=v1.x; a1.y+=v1.y; a1.z+=v1.z; a1.w+=v1.w;
        }
        for (; i < cnt; i += 4) {
            if (i + eo < cnt) {
                int s0 = csr[start + i + eo];
                float4 v0 = ld_h4(xw, s0, q);
                a0.x+=v0.x; a0.y+=v0.y; a0.z+=v0.z; a0.w+=v0.w;
            }
        }
        float4 acc;
        acc.x = a0.x+a1.x+a2.x+a3.x;
        acc.y = a0.y+a1.y+a2.y+a3.y;
        acc.z = a0.z+a1.z+a2.z+a3.z;
        acc.w = a0.w+a1.w+a2.w+a3.w;
        { float4 u = f4_shfl_xor(acc, 4); acc.x+=u.x; acc.y+=u.y; acc.z+=u.z; acc.w+=u.w; }
        { float4 u = f4_shfl_xor(acc, 8); acc.x+=u.x; acc.y+=u.y; acc.z+=u.z; acc.w+=u.w; }
        float4 sv = ld_h4(xw, node, q);
        float4 bq = ((const float4*)b2)[q];
        if (eo == 0) {
            m.x = fmaxf(dn * (acc.x + sv.x) + bq.x, 0.f);
            m.y = fmaxf(dn * (acc.y + sv.y) + bq.y, 0.f);
            m.z = fmaxf(dn * (acc.z + sv.z) + bq.z, 0.f);
            m.w = fmaxf(dn * (acc.w + sv.w) + bq.w, 0.f);
        }
    }
    { float4 u = f4_shfl_xor(m, 16); m.x+=u.x; m.y+=u.y; m.z+=u.z; m.w+=u.w; }
    { float4 u = f4_shfl_xor(m, 32); m.x+=u.x; m.y+=u.y; m.z+=u.z; m.w+=u.w; }
    __shared__ float smf[4][16];
    if (lane < 4) {
        smf[wave][q*4+0] = m.x;
        smf[wave][q*4+1] = m.y;
        smf[wave][q*4+2] = m.z;
        smf[wave][q*4+3] = m.w;
    }
    __syncthreads();
    if (threadIdx.x < 16) {
        float s = smf[0][threadIdx.x] + smf[1][threadIdx.x] + smf[2][threadIdx.x] + smf[3][threadIdx.x];
        partials[(size_t)blockIdx.x * 16 + threadIdx.x] = s;
    }
}

// ---------------- K8: final reduce + fc ----------------
__global__ void k_final(const float* __restrict__ partials, int NB, const float* __restrict__ fc_w,
                        const float* __restrict__ fc_b, float* __restrict__ out, float invN) {
    __shared__ float sm[64][16];
    int t = threadIdx.x;  // 1024 threads
    int g = t >> 4, j = t & 15;
    float s = 0.0f;
    for (int bk = g; bk < NB; bk += 64) s += partials[(size_t)bk * 16 + j];
    sm[g][j] = s;
    __syncthreads();
    for (int str = 32; str > 0; str >>= 1) {
        if (g < str) sm[g][j] += sm[g + str][j];
        __syncthreads();
    }
    if (t == 0) {
        float acc = fc_b[0];
#pragma unroll
        for (int jj = 0; jj < 16; jj++) acc += sm[0][jj] * invN * fc_w[jj];
        out[0] = acc;
    }
}

extern "C" void kernel_launch(void* const* d_in, const int* in_sizes, int n_in,
                              void* d_out, int out_size, void* d_ws, size_t ws_size,
                              hipStream_t stream) {
    const float* x   = (const float*)d_in[0];
    const int*   ei  = (const int*)d_in[1];
    const float* W1  = (const float*)d_in[2];
    const float* b1  = (const float*)d_in[3];
    const float* W2  = (const float*)d_in[4];
    const float* b2  = (const float*)d_in[5];
    const float* fcw = (const float*)d_in[6];
    const float* fcb = (const float*)d_in[7];
    float* out = (float*)d_out;

    int N = in_sizes[0] / F_IN;            // 100000
    int E = in_sizes[1] / 2;               // 3200000
    int K1 = (N + CB_W - 1) >> CB_SHIFT;   // 391 coarse buckets
    int B1 = (E + PER - 1) / PER;          // 512 partition blocks

    // ---- workspace carve-up (256B aligned) ----
    char* p = (char*)d_ws;
    auto alloc = [&](size_t bytes) {
        void* r = (void*)p;
        p += (bytes + 255) & ~(size_t)255;
        return r;
    };
    int*   cntT       = (int*)alloc((size_t)K1 * B1 * 4);
    int*   baseT      = (int*)alloc((size_t)K1 * B1 * 4);
    int*   bucketBase = (int*)alloc((size_t)K1 * 4);
    int*   bucketCnt  = (int*)alloc((size_t)K1 * 4);
    int*   hist       = (int*)alloc((size_t)N * 4);
    int*   offsets    = (int*)alloc((size_t)N * 4);
    float* dinv       = (float*)alloc((size_t)N * 4);
    int*   csr        = (int*)alloc((size_t)E * 4);
    unsigned* part    = (unsigned*)alloc((size_t)E * 4);    // 12.8 MB
    __half* xw1p      = (__half*)alloc((size_t)N * F_OUT * 2);  // 3.2 MB fp16
    __half* xw2p      = (__half*)alloc((size_t)N * F_OUT * 2);  // 3.2 MB fp16
    int NB_NODE = (N + 15) / 16;                            // 6250
    float* partials = (float*)alloc((size_t)NB_NODE * 16 * 4);

    k_chist<<<B1, 256, 0, stream>>>(ei, E, K1, B1, cntT);
    k_btot<<<1, 512, 0, stream>>>(cntT, B1, K1, bucketBase, bucketCnt);
    k_bbase<<<K1, 512, 0, stream>>>(cntT, B1, bucketBase, baseT);
    k_csort<<<B1, 512, 0, stream>>>(ei, E, K1, B1, cntT, baseT, part);
    k_prep2<<<K1, 512, 0, stream>>>(part, bucketBase, bucketCnt, hist, dinv, offsets, csr, N);

    k_gemm1<<<782, 256, 0, stream>>>(x, W1, dinv, xw1p, N);
    k_agg1<<<NB_NODE, 256, 0, stream>>>(xw1p, offsets, hist, dinv, csr, b1, W2, xw2p, N);
    k_agg2<<<NB_NODE, 256, 0, stream>>>(xw2p, offsets, hist, dinv, csr, b2, partials, N);
    k_final<<<1, 1024, 0, stream>>>(partials, NB_NODE, fcw, fcb, out, 1.0f / (float)N);
}